// Round 13
// baseline (769.460 us; speedup 1.0000x reference)
//
#include <hip/hip_runtime.h>
#include <math.h>

#define B 2
#define Q 15
#define U 20
#define C 64
#define HW 441
#define NW 5
#define MU (U*HW)      // 8820
#define MS HW          // 441
#define NJ (NW*MS)     // 2205
#define PD 64
#define LCAP NJ
#define BQN (B*Q*NW)   // 150
// Mutual-NN per (b,n) is injective into that class's 441 columns -> L <= 441,
// Lt = MS + L <= 882. 896 = 14*64 covers it.
#define LTCAP 896
#define SCAP 896
#define MSP 448
#define MUP 8832       // 69*128 (padded, zero beyond MU)
#define NJP 2304       // 18*128 (padded, zero beyond NJ)
#define NEGF (-3.402823466e38f)

// ---------------- device scratch (rewritten every call before any read) -----
__device__ unsigned long long g_snearpack[B*NJ];
__device__ unsigned long long g_unearpack[B*MU];
__device__ int   g_counts[B*NW];
__device__ int   g_L[1];
__device__ int   g_selidx[B*NW*LCAP];
__device__ float g_unln[(size_t)B*C*MUP];          // normalized unl, [b][c][m], padded
__device__ float g_supn[(size_t)B*C*NJP];          // normalized sup, [b][c][j], padded
__device__ float g_ksup[(size_t)B*NW*PD*LTCAP];
__device__ float g_vsup[(size_t)B*NW*PD*LTCAP];
__device__ float g_vsupT[(size_t)B*NW*LTCAP*PD];   // [b][n][l][o] transposed copy
__device__ float g_vbarn[B*NW*PD];
__device__ float g_qproj[(size_t)B*Q*PD*MSP];
__device__ float g_vqn[(size_t)B*Q*PD*MSP];
__device__ unsigned long long g_rowpack[(size_t)B*Q*NW*MSP];
__device__ unsigned long long g_snear2pack[(size_t)B*Q*NW*LTCAP];
__device__ int   g_qmrows[B*Q*MSP];
__device__ int   g_qmcount[B*Q];
__device__ unsigned g_cmax[(size_t)B*Q*NW*MSP];
__device__ float g_logits[B*Q*NW];
// scores from pass A, consumed by k_pv (zero-init; rows>=MS / cols>=Lt stay 0)
__device__ float g_scores[(size_t)B*Q*NW*MSP*SCAP];   // ~241MB
// pass B split buffers: partial PV accumulators (2 l-halves), partial lsums,
// finalized aligned rows, per-row inverse norms.
__device__ float g_accp[(size_t)2*BQN*MSP*PD];        // 34.4MB
__device__ float g_lsump[2*BQN*MSP];
__device__ float g_aligned[(size_t)BQN*MSP*PD];       // 17.2MB
__device__ float g_rnrow[BQN*MSP];

__device__ __forceinline__ unsigned enc_f(float f){
  unsigned b=__float_as_uint(f);
  return (b&0x80000000u)? ~b : (b|0x80000000u);
}
__device__ __forceinline__ float dec_f(unsigned k){
  unsigned b=(k&0x80000000u)?(k^0x80000000u):~k;
  return __uint_as_float(b);
}
__device__ __forceinline__ unsigned long long pk_make(float v,int idx){
  return ((unsigned long long)enc_f(v)<<32)|(unsigned)~(unsigned)idx;
}
__device__ __forceinline__ int pk_idx(unsigned long long p){
  return (int)~(unsigned)(p&0xFFFFFFFFull);
}

// ---------------- init ------------------------------------------------------
__global__ void k_init(){
  int i=blockIdx.x*256+threadIdx.x;
  if (i<B*NJ) g_snearpack[i]=0ull;
  if (i<B*MU) g_unearpack[i]=0ull;
  if (i<B*Q*NW*MSP){ g_rowpack[i]=0ull; g_cmax[i]=0u; }
  if (i<B*Q*NW*LTCAP) g_snear2pack[i]=0ull;
  // explicitly zero pad columns of the normalized copies (no reliance on
  // .bss zero-init / no poisoning hazard). unl pad: B*C*12; sup pad: B*C*99.
  if (i<B*C*(MUP-MU)){
    int b=i/(C*(MUP-MU)), r=i%(C*(MUP-MU)), c=r/(MUP-MU), m=MU+r%(MUP-MU);
    g_unln[((size_t)b*C+c)*MUP+m]=0.f;
  }
  if (i<B*C*(NJP-NJ)){
    int b=i/(C*(NJP-NJ)), r=i%(C*(NJP-NJ)), c=r/(NJP-NJ), j=NJ+r%(NJP-NJ);
    g_supn[((size_t)b*C+c)*NJP+j]=0.f;
  }
  if (i==0) g_L[0]=0;
}

// ---------------- K1: norms + normalized padded transposed copies -----------
__global__ void k_norms(const float* __restrict__ sup, const float* __restrict__ unl){
  int i=blockIdx.x*256+threadIdx.x;
  if (i<B*MU){
    int b=i/MU, m=i%MU, ui=m/HW, p=m%HW;
    const float* base=unl+((size_t)(b*U+ui)*C)*HW+p;
    float ss=0.f;
    for (int c=0;c<C;c++){ float x=base[(size_t)c*HW]; ss+=x*x; }
    float rn=1.f/fmaxf(sqrtf(ss),1e-12f);
    for (int c=0;c<C;c++) g_unln[((size_t)b*C+c)*MUP+m]=base[(size_t)c*HW]*rn;
  }
  if (i<B*NJ){
    int b=i/NJ, j=i%NJ, n=j/MS, s=j%MS;
    const float* base=sup+((size_t)(b*NW+n)*C)*HW+s;
    float ss=0.f;
    for (int c=0;c<C;c++){ float x=base[(size_t)c*HW]; ss+=x*x; }
    float rn=1.f/fmaxf(sqrtf(ss),1e-12f);
    for (int c=0;c<C;c++) g_supn[((size_t)b*C+c)*NJP+j]=base[(size_t)c*HW]*rn;
  }
}

// ---------------- K2: u2s — 128x128 tile, 8x8 micro, c-split halves ---------
__global__ __launch_bounds__(256) void k_u2s(){
  int blk=blockIdx.x;
  int jc=blk%18; blk/=18;
  int rb=blk%69; int b=blk/69;
  int m0=rb*128, j0=jc*128;
  int mv=min(128,MU-m0);
  int jv=min(128,NJ-j0);
  int tid=threadIdx.x, tm=tid>>4, tl=tid&15;
  int lane=tid&63, w=tid>>6;
  __shared__ __align__(16) float Ut[32*128];     // [c'][mm] 16KB
  __shared__ __align__(16) float Pt[32*128];     // [c'][jj] 16KB
  __shared__ unsigned long long colred[512];     // [w][128] 4KB
  const size_t ub=(size_t)b*C*MUP+m0;
  const size_t pb=(size_t)b*C*NJP+j0;
  float s[8][8]={};
  #pragma unroll
  for (int h=0;h<2;h++){
    __syncthreads();
    for (int k4=tid;k4<1024;k4+=256){
      int c=k4>>5, mq=k4&31;
      *(float4*)&Ut[c*128+mq*4]=*(const float4*)&g_unln[ub+(size_t)(h*32+c)*MUP+mq*4];
      *(float4*)&Pt[c*128+mq*4]=*(const float4*)&g_supn[pb+(size_t)(h*32+c)*NJP+mq*4];
    }
    __syncthreads();
    for (int c=0;c<32;c++){
      float a[8],b0[4],b1[4];
      *(float4*)&a[0]=*(const float4*)&Ut[c*128+tm*8];
      *(float4*)&a[4]=*(const float4*)&Ut[c*128+tm*8+4];
      *(float4*)b0=*(const float4*)&Pt[c*128+tl*4];
      *(float4*)b1=*(const float4*)&Pt[c*128+64+tl*4];
      #pragma unroll
      for (int i=0;i<8;i++)
        #pragma unroll
        for (int j=0;j<4;j++){ s[i][j]=fmaf(a[i],b0[j],s[i][j]); s[i][j+4]=fmaf(a[i],b1[j],s[i][j+4]); }
    }
  }
  // row-best over this chunk's 128 cols -> atomic merge across jc blocks
  #pragma unroll
  for (int i=0;i<8;i++){
    int mm=tm*8+i;
    unsigned long long p=0ull;
    if (mm<mv){
      #pragma unroll
      for (int j=0;j<8;j++){
        int jj=(j<4)?(tl*4+j):(64+tl*4+(j-4));
        if (jj<jv){
          unsigned long long c2=pk_make(s[i][j],j0+jj);
          if (c2>p) p=c2;
        }
      }
    }
    #pragma unroll
    for (int mk=1;mk<16;mk<<=1){ unsigned long long o=__shfl_xor(p,mk); if (o>p) p=o; }
    if (tl==0 && mm<mv && p) atomicMax(&g_unearpack[b*MU+m0+mm],p);
  }
  // col-best over this block's 128 rows -> atomic merge across rb blocks
  #pragma unroll
  for (int j=0;j<8;j++){
    int jj=(j<4)?(tl*4+j):(64+tl*4+(j-4));
    unsigned long long p=0ull;
    #pragma unroll
    for (int i=0;i<8;i++){
      int mm=tm*8+i;
      if (mm<mv){
        unsigned long long c2=pk_make(s[i][j],m0+mm);
        if (c2>p) p=c2;
      }
    }
    {
      unsigned long long o=__shfl_xor(p,16); if (o>p) p=o;
      o=__shfl_xor(p,32); if (o>p) p=o;
    }
    if ((lane>>4)==0) colred[w*128+jj]=p;
  }
  __syncthreads();
  if (tid<128 && tid<jv){
    unsigned long long p=colred[tid];
    if (colred[128+tid]>p) p=colred[128+tid];
    if (colred[256+tid]>p) p=colred[256+tid];
    if (colred[384+tid]>p) p=colred[384+tid];
    if (p) atomicMax(&g_snearpack[b*NJ+j0+tid],p);
  }
}

// ---------------- K4: mutual check + stable compaction; counts; L ----------
__global__ __launch_bounds__(256) void k_compact(){
  int b=blockIdx.x/NW, n=blockIdx.x%NW;
  int tid=threadIdx.x, lane=tid&63, w=tid>>6;
  __shared__ int wtot[4];
  int base=0;
  for (int m0=0;m0<MU;m0+=256){
    int m=m0+tid;
    bool flag=false;
    if (m<MU){
      int j=pk_idx(g_unearpack[b*MU+m]);
      flag=(j/MS==n) && (pk_idx(g_snearpack[b*NJ+j])==m);
    }
    unsigned long long bal=__ballot(flag);
    if (lane==0) wtot[w]=(int)__popcll(bal);
    __syncthreads();
    int wpre=0, tot=0;
    #pragma unroll
    for (int ww=0;ww<4;ww++){ if (ww<w) wpre+=wtot[ww]; tot+=wtot[ww]; }
    if (flag){
      int pre=(int)__popcll(bal&((1ull<<lane)-1ull));
      g_selidx[(b*NW+n)*LCAP+base+wpre+pre]=m;
    }
    base+=tot;
    __syncthreads();
  }
  if (tid==0){ g_counts[b*NW+n]=base; atomicMax(&g_L[0],base); }
}

// ---------------- K5: k_sup / v_sup / v_supT (zero-filled to Lt) ------------
__global__ __launch_bounds__(256) void k_kv(const float* __restrict__ sup, const float* __restrict__ unl,
                                            const float* __restrict__ kw, const float* __restrict__ vw){
  int blk=blockIdx.x;
  int lb=blk%(LTCAP/64); blk/=(LTCAP/64);
  int n=blk%NW, b=blk/NW;
  int Lt=MS+g_L[0];
  if (lb*64>=Lt) return;
  int cnt=g_counts[b*NW+n];
  int tid=threadIdx.x, lane=tid&63, w=tid>>6;
  __shared__ float F[4096];
  __shared__ const float* ptr_s[64];
  if (tid<64){
    int l=lb*64+tid;
    const float* p=nullptr;
    if (l<MS) p=&sup[((size_t)(b*NW+n)*C)*HW+l];
    else if (l<MS+cnt){
      int mg=g_selidx[(b*NW+n)*LCAP+(l-MS)];
      int ui=mg/HW, pp=mg%HW;
      p=&unl[((size_t)(b*U+ui)*C)*HW+pp];
    }
    ptr_s[tid]=p;
  }
  __syncthreads();
  for (int k=tid;k<4096;k+=256){
    int c=k>>6, ll=k&63;
    const float* p=ptr_s[ll];
    F[c*64+ll]=p?p[(size_t)c*HW]:0.f;
  }
  __syncthreads();
  int l=lb*64+lane;
  size_t ob=((size_t)(b*NW+n)*PD)*LTCAP+l;
  size_t tb=((size_t)(b*NW+n)*LTCAP+l)*PD;
  for (int oo=0;oo<16;oo++){
    int o=w*16+oo;
    float ka=0.f, va=0.f;
    for (int c=0;c<C;c++){ float f=F[c*64+lane]; ka=fmaf(kw[o*C+c],f,ka); va=fmaf(vw[o*C+c],f,va); }
    g_ksup[ob+(size_t)o*LTCAP]=ka;
    g_vsup[ob+(size_t)o*LTCAP]=va;
    g_vsupT[tb+o]=va;
  }
}

// ---------------- K5b: normalized vbar = mean_l v_sup, L2-normalized --------
__global__ __launch_bounds__(256) void k_vbar(){
  int bn=blockIdx.x;
  int tid=threadIdx.x, lane=tid&63, w=tid>>6;
  int cnt=g_counts[bn];
  int Lt=MS+g_L[0];
  __shared__ float vb_s[64];
  for (int oo=0;oo<16;oo++){
    int o=w*16+oo;
    const float* row=&g_vsup[((size_t)bn*PD+o)*LTCAP];
    float s=0.f;
    for (int l=lane;l<MS+cnt;l+=64) s+=row[l];
    #pragma unroll
    for (int mk=1;mk<64;mk<<=1) s+=__shfl_xor(s,mk);
    if (lane==0) vb_s[o]=s/(float)Lt;
  }
  __syncthreads();
  if (tid<64){
    float v=vb_s[tid];
    float ss=v*v;
    #pragma unroll
    for (int mk=1;mk<64;mk<<=1) ss+=__shfl_xor(ss,mk);
    g_vbarn[bn*PD+tid]=v/(sqrtf(ss)+1e-16f);
  }
}

// ---------------- K6: q_proj / normalized v_query (256 thr, o-split) --------
__global__ __launch_bounds__(256) void k_qproj(const float* __restrict__ qx, const float* __restrict__ qw,
                                               const float* __restrict__ vw){
  int blk=blockIdx.x;
  int mt=blk%7; blk/=7;
  int bq=blk;
  int tid=threadIdx.x, lane=tid&63, w=tid>>6;
  __shared__ float F[4096];
  __shared__ float ssp[256];
  for (int k=tid;k<4096;k+=256){
    int c=k>>6, mm=k&63, m=mt*64+mm;
    F[c*64+mm]=(m<MS)?qx[((size_t)bq*C+c)*HW+m]:0.f;
  }
  __syncthreads();
  int m=mt*64+lane;
  size_t ob=(size_t)bq*PD*MSP+m;
  float va[16]; float ssl=0.f;
  for (int oo=0;oo<16;oo++){
    int o=w*16+oo;
    float qa=0.f, v=0.f;
    for (int c=0;c<C;c++){ float f=F[c*64+lane]; qa=fmaf(qw[o*C+c],f,qa); v=fmaf(vw[o*C+c],f,v); }
    g_qproj[ob+(size_t)o*MSP]=qa;
    va[oo]=v; ssl=fmaf(v,v,ssl);
  }
  ssp[tid]=ssl;
  __syncthreads();
  float ss=ssp[lane]+ssp[64+lane]+ssp[128+lane]+ssp[192+lane];
  float rn=1.f/(sqrtf(ss)+1e-16f);
  for (int oo=0;oo<16;oo++) g_vqn[ob+(size_t)(w*16+oo)*MSP]=va[oo]*rn;
}

// ---------------- K7: pass A — 128x128 tile, 8x8 micro, c-split halves ------
__global__ __launch_bounds__(256) void k_passA(){
  int blk=blockIdx.x;
  int lc=blk%7; blk/=7;
  int mh=blk%4; blk/=4;
  int n=blk%NW; blk/=NW;
  int bq=blk; int b=bq/Q;
  int Lt=MS+g_L[0];
  int nch=(Lt+127)>>7;
  if (lc>=nch) return;
  int l0=lc<<7, lv=min(128,Lt-l0);
  int tid=threadIdx.x, tm=tid>>4, tl=tid&15;
  int lane=tid&63, w=tid>>6;
  int bqn=bq*NW+n;
  int m0=mh*128;
  __shared__ __align__(16) float Qt[32*128];     // [o'][mm] 16KB (half of c)
  __shared__ __align__(16) float Kt[32*128];     // [o'][jj] 16KB (half of c)
  __shared__ unsigned long long colred[512];     // [w][128] 4KB
  const size_t qb=(size_t)bq*PD*MSP;
  const size_t kb=(size_t)(b*NW+n)*PD*LTCAP;
  float s[8][8]={};
  #pragma unroll
  for (int h=0;h<2;h++){
    __syncthreads();               // h=1: protect tiles from overwrite
    for (int k4=tid;k4<1024;k4+=256){
      int o=k4>>5, mq=k4&31;       // o' in 0..31, mq in 0..31 (4 cols each)
      int m=m0+mq*4;
      float4 v=make_float4(0.f,0.f,0.f,0.f);
      if (m<MSP) v=*(const float4*)&g_qproj[qb+(size_t)(h*32+o)*MSP+m];
      *(float4*)&Qt[o*128+mq*4]=v;
      *(float4*)&Kt[o*128+mq*4]=*(const float4*)&g_ksup[kb+(size_t)(h*32+o)*LTCAP+l0+mq*4];
    }
    __syncthreads();
    for (int c=0;c<32;c++){
      float a[8],b0[4],b1[4];
      *(float4*)&a[0]=*(const float4*)&Qt[c*128+tm*8];
      *(float4*)&a[4]=*(const float4*)&Qt[c*128+tm*8+4];
      *(float4*)b0=*(const float4*)&Kt[c*128+tl*4];
      *(float4*)b1=*(const float4*)&Kt[c*128+64+tl*4];
      #pragma unroll
      for (int i=0;i<8;i++)
        #pragma unroll
        for (int j=0;j<4;j++){ s[i][j]=fmaf(a[i],b0[j],s[i][j]); s[i][j+4]=fmaf(a[i],b1[j],s[i][j+4]); }
    }
  }
  #pragma unroll
  for (int i=0;i<8;i++)
    #pragma unroll
    for (int j=0;j<8;j++) s[i][j]*=0.125f;
  // persist scores for pass B (cols beyond Lt are exact zeros via zero K)
  #pragma unroll
  for (int i=0;i<8;i++){
    int m=m0+tm*8+i;
    if (m<MS){
      size_t sbase=((size_t)bqn*MSP+m)*SCAP+l0;
      *(float4*)&g_scores[sbase+tl*4]   =make_float4(s[i][0],s[i][1],s[i][2],s[i][3]);
      *(float4*)&g_scores[sbase+64+tl*4]=make_float4(s[i][4],s[i][5],s[i][6],s[i][7]);
    }
  }
  // row-best over this chunk's 128 cols -> atomic merge across lc blocks
  #pragma unroll
  for (int i=0;i<8;i++){
    int m=m0+tm*8+i;
    unsigned long long p=0ull;
    if (m<MS){
      #pragma unroll
      for (int j=0;j<8;j++){
        int jj=(j<4)?(tl*4+j):(64+tl*4+(j-4));
        if (jj<lv){
          unsigned long long c2=pk_make(s[i][j],l0+jj);
          if (c2>p) p=c2;
        }
      }
    }
    #pragma unroll
    for (int mk=1;mk<16;mk<<=1){ unsigned long long o=__shfl_xor(p,mk); if (o>p) p=o; }
    if (tl==0 && m<MS && p) atomicMax(&g_rowpack[(size_t)bqn*MSP+m],p);
  }
  // col-best over this block's 128 rows -> atomic merge across mh blocks
  #pragma unroll
  for (int j=0;j<8;j++){
    int jj=(j<4)?(tl*4+j):(64+tl*4+(j-4));
    unsigned long long p=0ull;
    #pragma unroll
    for (int i=0;i<8;i++){
      int m=m0+tm*8+i;
      if (m<MS){
        unsigned long long c2=pk_make(s[i][j],m);
        if (c2>p) p=c2;
      }
    }
    {
      unsigned long long o=__shfl_xor(p,16); if (o>p) p=o;
      o=__shfl_xor(p,32); if (o>p) p=o;
    }
    if ((lane>>4)==0) colred[w*128+jj]=p;
  }
  __syncthreads();
  if (tid<128 && tid<lv){
    unsigned long long p=colred[tid];
    if (colred[128+tid]>p) p=colred[128+tid];
    if (colred[256+tid]>p) p=colred[256+tid];
    if (colred[384+tid]>p) p=colred[384+tid];
    if (p) atomicMax(&g_snear2pack[(size_t)bqn*LTCAP+l0+tid],p);
  }
}

// ---------------- K8: q_mask + masked-row compaction ------------------------
__global__ __launch_bounds__(256) void k_qmask(){
  int bq=blockIdx.x;
  int tid=threadIdx.x, lane=tid&63, w=tid>>6;
  __shared__ int wtot[4];
  int base=0;
  for (int m0=0;m0<MS;m0+=256){
    int m=m0+tid;
    bool qm=false;
    if (m<MS){
      unsigned bhv=0u; unsigned long long bp=0ull; int bn=0;
      #pragma unroll
      for (int n=0;n<NW;n++){
        unsigned long long pk=g_rowpack[(size_t)(bq*NW+n)*MSP+m];
        unsigned hv=(unsigned)(pk>>32);
        if (hv>bhv){bhv=hv;bp=pk;bn=n;}
      }
      int bl=pk_idx(bp);
      qm=(pk_idx(g_snear2pack[(size_t)(bq*NW+bn)*LTCAP+bl])==m);
    }
    unsigned long long bal=__ballot(qm);
    if (lane==0) wtot[w]=(int)__popcll(bal);
    __syncthreads();
    int wpre=0, tot=0;
    #pragma unroll
    for (int ww=0;ww<4;ww++){ if (ww<w) wpre+=wtot[ww]; tot+=wtot[ww]; }
    if (qm){
      int pre=(int)__popcll(bal&((1ull<<lane)-1ull));
      g_qmrows[bq*MSP+base+wpre+pre]=m;
    }
    base+=tot;
    __syncthreads();
  }
  if (tid==0) g_qmcount[bq]=base;
}

// ---------------- K9a: pass B part 1 — PV partials over l-halves ------------
// Round-7 phase-A structure (34KB LDS class, (256,4), named prefetch regs —
// the verified non-spilling config), with the l-chunks split across 2 blocks
// (lh): 1200 active blocks vs 600 -> fills the 4-block/CU LDS residency.
// Writes UN-normalized partial acc + partial lsum; k_fin combines.
#define EXPROW(i, svi) { \
    float e0=(tl*4+0<lv)?__expf((svi).x-rmax[i]):0.f; \
    float e1=(tl*4+1<lv)?__expf((svi).y-rmax[i]):0.f; \
    float e2=(tl*4+2<lv)?__expf((svi).z-rmax[i]):0.f; \
    float e3=(tl*4+3<lv)?__expf((svi).w-rmax[i]):0.f; \
    lsum[i]+=(e0+e1)+(e2+e3); \
    *(float4*)&Pt[(tm*4+(i))*68+tl*4]=make_float4(e0,e1,e2,e3); }
__global__ __launch_bounds__(256,4) void k_pv(){
  int blk=blockIdx.x;
  int lh=blk&1; blk>>=1;
  int rt=blk%7; blk/=7;
  int n=blk%NW; blk/=NW;
  int bq=blk; int b=bq/Q;
  int nm=g_qmcount[bq];
  if (rt*64>=nm) return;
  int bqn=bq*NW+n;
  int Lt=MS+g_L[0];
  int nch=(Lt+63)>>6;
  int c0=lh*7, c1=min(nch,c0+7);
  int tid=threadIdx.x, tm=tid>>4, tl=tid&15;
  __shared__ __align__(16) float Vt[4096];     // V chunk [l][o]
  __shared__ __align__(16) float Pt[64*68];    // stride 68: 16B-aligned rows
  __shared__ int rows_s[64];
  if (tid<64){ int g=rt*64+tid; rows_s[tid]=(g<nm)?g_qmrows[bq*MSP+g]:0; }
  __syncthreads();
  float rmax[4]; size_t sb[4];
  #pragma unroll
  for (int i=0;i<4;i++){
    int row=rows_s[tm*4+i];
    rmax[i]=dec_f((unsigned)(g_rowpack[(size_t)bqn*MSP+row]>>32));
    sb[i]=((size_t)bqn*MSP+row)*SCAP;
  }
  const size_t vb=(size_t)(b*NW+n)*LTCAP*PD;
  float lsum[4]={0.f,0.f,0.f,0.f};
  float acc[4][4]={};
  if (c0<c1){
    // prologue prefetch: chunk c0 scores + V (named regs, not arrays)
    float4 sv0,sv1,sv2,sv3, vp0,vp1,vp2,vp3;
    {
      int l0=c0<<6;
      sv0=*(const float4*)&g_scores[sb[0]+l0+tl*4];
      sv1=*(const float4*)&g_scores[sb[1]+l0+tl*4];
      sv2=*(const float4*)&g_scores[sb[2]+l0+tl*4];
      sv3=*(const float4*)&g_scores[sb[3]+l0+tl*4];
      const float* src=&g_vsupT[vb+(size_t)l0*PD];
      vp0=*(const float4*)&src[(tid     )*4];
      vp1=*(const float4*)&src[(tid+256 )*4];
      vp2=*(const float4*)&src[(tid+512 )*4];
      vp3=*(const float4*)&src[(tid+768 )*4];
    }
    for (int lc=c0;lc<c1;lc++){
      int l0=lc<<6, lv=min(64,Lt-l0);
      __syncthreads();                       // prev PV reads of Vt/Pt done
      *(float4*)&Vt[(tid     )*4]=vp0;
      *(float4*)&Vt[(tid+256 )*4]=vp1;
      *(float4*)&Vt[(tid+512 )*4]=vp2;
      *(float4*)&Vt[(tid+768 )*4]=vp3;
      EXPROW(0,sv0) EXPROW(1,sv1) EXPROW(2,sv2) EXPROW(3,sv3)
      __syncthreads();                       // Pt/Vt ready
      if (lc+1<c1){
        int l1=(lc+1)<<6;
        sv0=*(const float4*)&g_scores[sb[0]+l1+tl*4];
        sv1=*(const float4*)&g_scores[sb[1]+l1+tl*4];
        sv2=*(const float4*)&g_scores[sb[2]+l1+tl*4];
        sv3=*(const float4*)&g_scores[sb[3]+l1+tl*4];
        const float* src=&g_vsupT[vb+(size_t)l1*PD];
        vp0=*(const float4*)&src[(tid     )*4];
        vp1=*(const float4*)&src[(tid+256 )*4];
        vp2=*(const float4*)&src[(tid+512 )*4];
        vp3=*(const float4*)&src[(tid+768 )*4];
      }
      for (int l4=0;l4<64;l4+=4){
        float4 pq[4];
        #pragma unroll
        for (int i=0;i<4;i++) pq[i]=*(const float4*)&Pt[(tm*4+i)*68+l4];
        #pragma unroll
        for (int u=0;u<4;u++){
          float4 v4=*(const float4*)&Vt[(l4+u)*64+tl*4];
          #pragma unroll
          for (int i=0;i<4;i++){
            float p=((const float*)&pq[i])[u];
            acc[i][0]=fmaf(p,v4.x,acc[i][0]);
            acc[i][1]=fmaf(p,v4.y,acc[i][1]);
            acc[i][2]=fmaf(p,v4.z,acc[i][2]);
            acc[i][3]=fmaf(p,v4.w,acc[i][3]);
          }
        }
      }
    }
  }
  // store partials (zeros if this half had no chunks)
  const size_t lbase=((size_t)lh*BQN+bqn)*MSP;
  #pragma unroll
  for (int i=0;i<4;i++){
    float ls=lsum[i];
    #pragma unroll
    for (int mk=1;mk<16;mk<<=1) ls+=__shfl_xor(ls,mk);
    int g=rt*64+tm*4+i;
    if (tl==0) g_lsump[lbase+g]=ls;
    *(float4*)&g_accp[(lbase+g)*PD+tl*4]=make_float4(acc[i][0],acc[i][1],acc[i][2],acc[i][3]);
  }
}

// ---------------- K9b: combine halves, normalize, L2-normalize --------------
__global__ __launch_bounds__(256) void k_fin(){
  int blk=blockIdx.x;
  int rt=blk%7; blk/=7;
  int n=blk%NW; blk/=NW;
  int bq=blk;
  int nm=g_qmcount[bq];
  if (rt*64>=nm) return;
  int bqn=bq*NW+n;
  int tid=threadIdx.x, tm=tid>>4, tl=tid&15;
  #pragma unroll
  for (int i=0;i<4;i++){
    int g=rt*64+tm*4+i;
    size_t r0=(size_t)bqn*MSP+g;
    size_t r1=(size_t)(BQN+bqn)*MSP+g;
    float4 a0=*(const float4*)&g_accp[r0*PD+tl*4];
    float4 a1=*(const float4*)&g_accp[r1*PD+tl*4];
    float ls=g_lsump[r0]+g_lsump[r1];
    float a[4]={a0.x+a1.x, a0.y+a1.y, a0.z+a1.z, a0.w+a1.w};
    float ss=0.f;
    #pragma unroll
    for (int j=0;j<4;j++){ a[j]/=ls; ss=fmaf(a[j],a[j],ss); }
    #pragma unroll
    for (int mk=1;mk<16;mk<<=1) ss+=__shfl_xor(ss,mk);
    float rn=1.f/(sqrtf(ss)+1e-16f);
    *(float4*)&g_aligned[r0*PD+tl*4]=make_float4(a[0],a[1],a[2],a[3]);
    if (tl==0) g_rnrow[r0]=rn;
  }
}

// ---------------- K9c: simi2 — d = aligned·vqn; col-max into cmax -----------
// grid (bqn, rt, kt): 4200 active blocks -> full residency; tiny GEMM each.
__global__ __launch_bounds__(256) void k_simi2(){
  int blk=blockIdx.x;
  int kt=blk%7; blk/=7;
  int rt=blk%7; blk/=7;
  int n=blk%NW; blk/=NW;
  int bq=blk;
  int nm=g_qmcount[bq];
  if (rt*64>=nm) return;
  int bqn=bq*NW+n;
  int tid=threadIdx.x, tm=tid>>4, tl=tid&15;
  __shared__ __align__(16) float Vt[4096];     // vqn tile [o][k]
  __shared__ __align__(16) float Pt[64*68];    // aligned rows
  __shared__ float rn_s[64];
  const size_t qb=(size_t)bq*PD*MSP;
  for (int k=tid;k<1024;k+=256){
    int r=k>>4, oq=k&15;
    *(float4*)&Pt[r*68+oq*4]=*(const float4*)&g_aligned[((size_t)bqn*MSP+rt*64+r)*PD+oq*4];
  }
  if (tid<64) rn_s[tid]=g_rnrow[(size_t)bqn*MSP+rt*64+tid];
  for (int k=tid;k<1024;k+=256){
    int o=k>>4, kq=k&15;
    *(float4*)&Vt[o*64+kq*4]=*(const float4*)&g_vqn[qb+(size_t)o*MSP+kt*64+kq*4];
  }
  __syncthreads();
  float d[4][4]={};
  for (int o=0;o<64;o++){
    float a[4], bv4[4];
    #pragma unroll
    for (int i=0;i<4;i++) a[i]=Pt[(tm*4+i)*68+o];
    *(float4*)bv4=*(const float4*)&Vt[o*64+tl*4];
    #pragma unroll
    for (int i=0;i<4;i++)
      #pragma unroll
      for (int j=0;j<4;j++) d[i][j]=fmaf(a[i],bv4[j],d[i][j]);
  }
  int rowok[4]; float rn[4];
  #pragma unroll
  for (int i=0;i<4;i++){ rowok[i]=(rt*64+tm*4+i<nm); rn[i]=rn_s[tm*4+i]; }
  #pragma unroll
  for (int j=0;j<4;j++){
    int kg=kt*64+tl*4+j;
    float mv=NEGF;
    #pragma unroll
    for (int i=0;i<4;i++) if (rowok[i]) mv=fmaxf(mv,d[i][j]*rn[i]);
    mv=fmaxf(mv,__shfl_xor(mv,16));
    mv=fmaxf(mv,__shfl_xor(mv,32));
    if (((tid>>4)&3)==0 && kg<MS && mv>-1e37f)
      atomicMax(&g_cmax[(size_t)bqn*MSP+kg],enc_f(mv));
  }
}

// ---------------- K10: logits (with fused vbar contribution) ----------------
__global__ __launch_bounds__(256) void k_logits(){
  int bqn=blockIdx.x;
  int n=bqn%NW, bq=bqn/NW, b=bq/Q;
  int tid=threadIdx.x;
  int nm=g_qmcount[bq];
  __shared__ float red[256];
  __shared__ float vb_s[64];
  if (tid<64) vb_s[tid]=g_vbarn[(b*NW+n)*PD+tid];
  __syncthreads();
  const float* vq=&g_vqn[(size_t)bq*PD*MSP];
  float p=0.f;
  for (int k=tid;k<MS;k+=256){
    float v=dec_f(g_cmax[(size_t)bqn*MSP+k]);
    if (nm<MS){
      float d=0.f;
      for (int o=0;o<PD;o++) d=fmaf(vb_s[o],vq[(size_t)o*MSP+k],d);
      v=fmaxf(v,d);
    }
    p+=(v+1.f)*0.5f;
  }
  red[tid]=p; __syncthreads();
  for (int s=128;s;s>>=1){ if (tid<s) red[tid]+=red[tid+s]; __syncthreads(); }
  if (tid==0) g_logits[bqn]=red[0];
}

// ---------------- K11: NLL loss ---------------------------------------------
__global__ void k_loss(const int* __restrict__ qy, float* __restrict__ out){
  int t=threadIdx.x;
  float lp=0.f;
  if (t<B*Q){
    int y=qy[t];
    float xv[NW]; float mxv=NEGF;
    #pragma unroll
    for (int n=0;n<NW;n++){ xv[n]=g_logits[t*NW+n]*5.f; mxv=fmaxf(mxv,xv[n]); }
    float s=0.f, xy=0.f;
    #pragma unroll
    for (int n=0;n<NW;n++){ s+=__expf(xv[n]-mxv); if (n==y) xy=xv[n]; }
    lp=xy-mxv-logf(s);
  }
  #pragma unroll
  for (int off=32;off;off>>=1) lp+=__shfl_down(lp,off);
  if (t==0) out[0]=-lp/(float)(B*Q);
}

extern "C" void kernel_launch(void* const* d_in, const int* in_sizes, int n_in,
                              void* d_out, int out_size, void* d_ws, size_t ws_size,
                              hipStream_t stream) {
  (void)in_sizes; (void)n_in; (void)out_size; (void)d_ws; (void)ws_size;
  const float* sup=(const float*)d_in[0];
  const float* qx =(const float*)d_in[2];
  const int*   qy =(const int*)d_in[3];
  const float* unl=(const float*)d_in[4];
  const float* kw =(const float*)d_in[5];
  const float* qw =(const float*)d_in[6];
  const float* vw =(const float*)d_in[7];
  float* out=(float*)d_out;

  k_init   <<<525,256,0,stream>>>();     // covers B*Q*NW*LTCAP = 134400
  k_norms  <<<69,256,0,stream>>>(sup,unl);
  k_u2s    <<<B*69*18,256,0,stream>>>();
  k_compact<<<B*NW,256,0,stream>>>();
  k_kv     <<<B*NW*(LTCAP/64),256,0,stream>>>(sup,unl,kw,vw);
  k_vbar   <<<B*NW,256,0,stream>>>();
  k_qproj  <<<B*Q*7,256,0,stream>>>(qx,qw,vw);
  k_passA  <<<B*Q*NW*28,256,0,stream>>>();
  k_qmask  <<<B*Q,256,0,stream>>>();
  k_pv     <<<B*Q*NW*7*2,256,0,stream>>>();
  k_fin    <<<B*Q*NW*7,256,0,stream>>>();
  k_simi2  <<<B*Q*NW*7*7,256,0,stream>>>();
  k_logits <<<B*Q*NW,256,0,stream>>>();
  k_loss   <<<1,64,0,stream>>>(qy,out);
}

// Round 15
// 651.228 us; speedup vs baseline: 1.1816x; 1.1816x over previous
//
#include <hip/hip_runtime.h>
#include <math.h>

#define B 2
#define Q 15
#define U 20
#define C 64
#define HW 441
#define NW 5
#define MU (U*HW)      // 8820
#define MS HW          // 441
#define NJ (NW*MS)     // 2205
#define PD 64
#define LCAP NJ
// Mutual-NN per (b,n) is injective into that class's 441 columns -> L <= 441,
// Lt = MS + L <= 882. 896 = 14*64 covers it.
#define LTCAP 896
#define SCAP 896
#define MSP 448
#define MUP 8832       // 69*128 (padded, zero beyond MU)
#define NJP 2304       // 18*128 (padded, zero beyond NJ)
#define NEGF (-3.402823466e38f)

// ---------------- device scratch (rewritten every call before any read) -----
__device__ unsigned long long g_snearpack[B*NJ];
__device__ unsigned long long g_unearpack[B*MU];
__device__ int   g_counts[B*NW];
__device__ int   g_L[1];
__device__ int   g_selidx[B*NW*LCAP];
__device__ float g_unln[(size_t)B*C*MUP];          // normalized unl, [b][c][m], padded
__device__ float g_supn[(size_t)B*C*NJP];          // normalized sup, [b][c][j], padded
__device__ float g_ksup[(size_t)B*NW*PD*LTCAP];
__device__ float g_vsup[(size_t)B*NW*PD*LTCAP];
__device__ float g_vsupT[(size_t)B*NW*LTCAP*PD];   // [b][n][l][o] transposed copy
__device__ float g_vbarn[B*NW*PD];
__device__ float g_qproj[(size_t)B*Q*PD*MSP];
__device__ float g_vqn[(size_t)B*Q*PD*MSP];
__device__ unsigned long long g_rowpack[(size_t)B*Q*NW*MSP];
__device__ unsigned long long g_snear2pack[(size_t)B*Q*NW*LTCAP];
__device__ int   g_qmrows[B*Q*MSP];
__device__ int   g_qmcount[B*Q];
__device__ unsigned g_cmax[(size_t)B*Q*NW*MSP];
__device__ float g_logits[B*Q*NW];
// scores from pass A, consumed by pass B (zero-init; rows>=MS / cols>=Lt stay 0)
__device__ float g_scores[(size_t)B*Q*NW*MSP*SCAP];   // ~241MB

__device__ __forceinline__ unsigned enc_f(float f){
  unsigned b=__float_as_uint(f);
  return (b&0x80000000u)? ~b : (b|0x80000000u);
}
__device__ __forceinline__ float dec_f(unsigned k){
  unsigned b=(k&0x80000000u)?(k^0x80000000u):~k;
  return __uint_as_float(b);
}
__device__ __forceinline__ unsigned long long pk_make(float v,int idx){
  return ((unsigned long long)enc_f(v)<<32)|(unsigned)~(unsigned)idx;
}
__device__ __forceinline__ int pk_idx(unsigned long long p){
  return (int)~(unsigned)(p&0xFFFFFFFFull);
}

// ---------------- init ------------------------------------------------------
__global__ void k_init(){
  int i=blockIdx.x*256+threadIdx.x;
  if (i<B*NJ) g_snearpack[i]=0ull;
  if (i<B*MU) g_unearpack[i]=0ull;
  if (i<B*Q*NW*MSP){ g_rowpack[i]=0ull; g_cmax[i]=0u; }
  if (i<B*Q*NW*LTCAP) g_snear2pack[i]=0ull;
  // explicitly zero pad columns of the normalized copies (no reliance on
  // .bss zero-init / no poisoning hazard). unl pad: B*C*12; sup pad: B*C*99.
  if (i<B*C*(MUP-MU)){
    int b=i/(C*(MUP-MU)), r=i%(C*(MUP-MU)), c=r/(MUP-MU), m=MU+r%(MUP-MU);
    g_unln[((size_t)b*C+c)*MUP+m]=0.f;
  }
  if (i<B*C*(NJP-NJ)){
    int b=i/(C*(NJP-NJ)), r=i%(C*(NJP-NJ)), c=r/(NJP-NJ), j=NJ+r%(NJP-NJ);
    g_supn[((size_t)b*C+c)*NJP+j]=0.f;
  }
  if (i==0) g_L[0]=0;
}

// ---------------- K1: norms + normalized padded transposed copies -----------
__global__ void k_norms(const float* __restrict__ sup, const float* __restrict__ unl){
  int i=blockIdx.x*256+threadIdx.x;
  if (i<B*MU){
    int b=i/MU, m=i%MU, ui=m/HW, p=m%HW;
    const float* base=unl+((size_t)(b*U+ui)*C)*HW+p;
    float ss=0.f;
    for (int c=0;c<C;c++){ float x=base[(size_t)c*HW]; ss+=x*x; }
    float rn=1.f/fmaxf(sqrtf(ss),1e-12f);
    for (int c=0;c<C;c++) g_unln[((size_t)b*C+c)*MUP+m]=base[(size_t)c*HW]*rn;
  }
  if (i<B*NJ){
    int b=i/NJ, j=i%NJ, n=j/MS, s=j%MS;
    const float* base=sup+((size_t)(b*NW+n)*C)*HW+s;
    float ss=0.f;
    for (int c=0;c<C;c++){ float x=base[(size_t)c*HW]; ss+=x*x; }
    float rn=1.f/fmaxf(sqrtf(ss),1e-12f);
    for (int c=0;c<C;c++) g_supn[((size_t)b*C+c)*NJP+j]=base[(size_t)c*HW]*rn;
  }
}

// ---------------- K2: u2s — 128x128 tile, 8x8 micro, c-split halves ---------
__global__ __launch_bounds__(256) void k_u2s(){
  int blk=blockIdx.x;
  int jc=blk%18; blk/=18;
  int rb=blk%69; int b=blk/69;
  int m0=rb*128, j0=jc*128;
  int mv=min(128,MU-m0);
  int jv=min(128,NJ-j0);
  int tid=threadIdx.x, tm=tid>>4, tl=tid&15;
  int lane=tid&63, w=tid>>6;
  __shared__ __align__(16) float Ut[32*128];     // [c'][mm] 16KB
  __shared__ __align__(16) float Pt[32*128];     // [c'][jj] 16KB
  __shared__ unsigned long long colred[512];     // [w][128] 4KB
  const size_t ub=(size_t)b*C*MUP+m0;
  const size_t pb=(size_t)b*C*NJP+j0;
  float s[8][8]={};
  #pragma unroll
  for (int h=0;h<2;h++){
    __syncthreads();
    for (int k4=tid;k4<1024;k4+=256){
      int c=k4>>5, mq=k4&31;
      *(float4*)&Ut[c*128+mq*4]=*(const float4*)&g_unln[ub+(size_t)(h*32+c)*MUP+mq*4];
      *(float4*)&Pt[c*128+mq*4]=*(const float4*)&g_supn[pb+(size_t)(h*32+c)*NJP+mq*4];
    }
    __syncthreads();
    for (int c=0;c<32;c++){
      float a[8],b0[4],b1[4];
      *(float4*)&a[0]=*(const float4*)&Ut[c*128+tm*8];
      *(float4*)&a[4]=*(const float4*)&Ut[c*128+tm*8+4];
      *(float4*)b0=*(const float4*)&Pt[c*128+tl*4];
      *(float4*)b1=*(const float4*)&Pt[c*128+64+tl*4];
      #pragma unroll
      for (int i=0;i<8;i++)
        #pragma unroll
        for (int j=0;j<4;j++){ s[i][j]=fmaf(a[i],b0[j],s[i][j]); s[i][j+4]=fmaf(a[i],b1[j],s[i][j+4]); }
    }
  }
  // row-best over this chunk's 128 cols -> atomic merge across jc blocks
  #pragma unroll
  for (int i=0;i<8;i++){
    int mm=tm*8+i;
    unsigned long long p=0ull;
    if (mm<mv){
      #pragma unroll
      for (int j=0;j<8;j++){
        int jj=(j<4)?(tl*4+j):(64+tl*4+(j-4));
        if (jj<jv){
          unsigned long long c2=pk_make(s[i][j],j0+jj);
          if (c2>p) p=c2;
        }
      }
    }
    #pragma unroll
    for (int mk=1;mk<16;mk<<=1){ unsigned long long o=__shfl_xor(p,mk); if (o>p) p=o; }
    if (tl==0 && mm<mv && p) atomicMax(&g_unearpack[b*MU+m0+mm],p);
  }
  // col-best over this block's 128 rows -> atomic merge across rb blocks
  #pragma unroll
  for (int j=0;j<8;j++){
    int jj=(j<4)?(tl*4+j):(64+tl*4+(j-4));
    unsigned long long p=0ull;
    #pragma unroll
    for (int i=0;i<8;i++){
      int mm=tm*8+i;
      if (mm<mv){
        unsigned long long c2=pk_make(s[i][j],m0+mm);
        if (c2>p) p=c2;
      }
    }
    {
      unsigned long long o=__shfl_xor(p,16); if (o>p) p=o;
      o=__shfl_xor(p,32); if (o>p) p=o;
    }
    if ((lane>>4)==0) colred[w*128+jj]=p;
  }
  __syncthreads();
  if (tid<128 && tid<jv){
    unsigned long long p=colred[tid];
    if (colred[128+tid]>p) p=colred[128+tid];
    if (colred[256+tid]>p) p=colred[256+tid];
    if (colred[384+tid]>p) p=colred[384+tid];
    if (p) atomicMax(&g_snearpack[b*NJ+j0+tid],p);
  }
}

// ---------------- K4: mutual check + stable compaction; counts; L ----------
__global__ __launch_bounds__(256) void k_compact(){
  int b=blockIdx.x/NW, n=blockIdx.x%NW;
  int tid=threadIdx.x, lane=tid&63, w=tid>>6;
  __shared__ int wtot[4];
  int base=0;
  for (int m0=0;m0<MU;m0+=256){
    int m=m0+tid;
    bool flag=false;
    if (m<MU){
      int j=pk_idx(g_unearpack[b*MU+m]);
      flag=(j/MS==n) && (pk_idx(g_snearpack[b*NJ+j])==m);
    }
    unsigned long long bal=__ballot(flag);
    if (lane==0) wtot[w]=(int)__popcll(bal);
    __syncthreads();
    int wpre=0, tot=0;
    #pragma unroll
    for (int ww=0;ww<4;ww++){ if (ww<w) wpre+=wtot[ww]; tot+=wtot[ww]; }
    if (flag){
      int pre=(int)__popcll(bal&((1ull<<lane)-1ull));
      g_selidx[(b*NW+n)*LCAP+base+wpre+pre]=m;
    }
    base+=tot;
    __syncthreads();
  }
  if (tid==0){ g_counts[b*NW+n]=base; atomicMax(&g_L[0],base); }
}

// ---------------- K5: k_sup / v_sup / v_supT (zero-filled to Lt) ------------
__global__ __launch_bounds__(256) void k_kv(const float* __restrict__ sup, const float* __restrict__ unl,
                                            const float* __restrict__ kw, const float* __restrict__ vw){
  int blk=blockIdx.x;
  int lb=blk%(LTCAP/64); blk/=(LTCAP/64);
  int n=blk%NW, b=blk/NW;
  int Lt=MS+g_L[0];
  if (lb*64>=Lt) return;
  int cnt=g_counts[b*NW+n];
  int tid=threadIdx.x, lane=tid&63, w=tid>>6;
  __shared__ float F[4096];
  __shared__ const float* ptr_s[64];
  if (tid<64){
    int l=lb*64+tid;
    const float* p=nullptr;
    if (l<MS) p=&sup[((size_t)(b*NW+n)*C)*HW+l];
    else if (l<MS+cnt){
      int mg=g_selidx[(b*NW+n)*LCAP+(l-MS)];
      int ui=mg/HW, pp=mg%HW;
      p=&unl[((size_t)(b*U+ui)*C)*HW+pp];
    }
    ptr_s[tid]=p;
  }
  __syncthreads();
  for (int k=tid;k<4096;k+=256){
    int c=k>>6, ll=k&63;
    const float* p=ptr_s[ll];
    F[c*64+ll]=p?p[(size_t)c*HW]:0.f;
  }
  __syncthreads();
  int l=lb*64+lane;
  size_t ob=((size_t)(b*NW+n)*PD)*LTCAP+l;
  size_t tb=((size_t)(b*NW+n)*LTCAP+l)*PD;
  for (int oo=0;oo<16;oo++){
    int o=w*16+oo;
    float ka=0.f, va=0.f;
    for (int c=0;c<C;c++){ float f=F[c*64+lane]; ka=fmaf(kw[o*C+c],f,ka); va=fmaf(vw[o*C+c],f,va); }
    g_ksup[ob+(size_t)o*LTCAP]=ka;
    g_vsup[ob+(size_t)o*LTCAP]=va;
    g_vsupT[tb+o]=va;
  }
}

// ---------------- K5b: normalized vbar = mean_l v_sup, L2-normalized --------
__global__ __launch_bounds__(256) void k_vbar(){
  int bn=blockIdx.x;
  int tid=threadIdx.x, lane=tid&63, w=tid>>6;
  int cnt=g_counts[bn];
  int Lt=MS+g_L[0];
  __shared__ float vb_s[64];
  for (int oo=0;oo<16;oo++){
    int o=w*16+oo;
    const float* row=&g_vsup[((size_t)bn*PD+o)*LTCAP];
    float s=0.f;
    for (int l=lane;l<MS+cnt;l+=64) s+=row[l];
    #pragma unroll
    for (int mk=1;mk<64;mk<<=1) s+=__shfl_xor(s,mk);
    if (lane==0) vb_s[o]=s/(float)Lt;
  }
  __syncthreads();
  if (tid<64){
    float v=vb_s[tid];
    float ss=v*v;
    #pragma unroll
    for (int mk=1;mk<64;mk<<=1) ss+=__shfl_xor(ss,mk);
    g_vbarn[bn*PD+tid]=v/(sqrtf(ss)+1e-16f);
  }
}

// ---------------- K6: q_proj / normalized v_query (256 thr, o-split) --------
__global__ __launch_bounds__(256) void k_qproj(const float* __restrict__ qx, const float* __restrict__ qw,
                                               const float* __restrict__ vw){
  int blk=blockIdx.x;
  int mt=blk%7; blk/=7;
  int bq=blk;
  int tid=threadIdx.x, lane=tid&63, w=tid>>6;
  __shared__ float F[4096];
  __shared__ float ssp[256];
  for (int k=tid;k<4096;k+=256){
    int c=k>>6, mm=k&63, m=mt*64+mm;
    F[c*64+mm]=(m<MS)?qx[((size_t)bq*C+c)*HW+m]:0.f;
  }
  __syncthreads();
  int m=mt*64+lane;
  size_t ob=(size_t)bq*PD*MSP+m;
  float va[16]; float ssl=0.f;
  for (int oo=0;oo<16;oo++){
    int o=w*16+oo;
    float qa=0.f, v=0.f;
    for (int c=0;c<C;c++){ float f=F[c*64+lane]; qa=fmaf(qw[o*C+c],f,qa); v=fmaf(vw[o*C+c],f,v); }
    g_qproj[ob+(size_t)o*MSP]=qa;
    va[oo]=v; ssl=fmaf(v,v,ssl);
  }
  ssp[tid]=ssl;
  __syncthreads();
  float ss=ssp[lane]+ssp[64+lane]+ssp[128+lane]+ssp[192+lane];
  float rn=1.f/(sqrtf(ss)+1e-16f);
  for (int oo=0;oo<16;oo++) g_vqn[ob+(size_t)(w*16+oo)*MSP]=va[oo]*rn;
}

// ---------------- K7: pass A — 128x128 tile, 8x8 micro, c-split halves ------
__global__ __launch_bounds__(256) void k_passA(){
  int blk=blockIdx.x;
  int lc=blk%7; blk/=7;
  int mh=blk%4; blk/=4;
  int n=blk%NW; blk/=NW;
  int bq=blk; int b=bq/Q;
  int Lt=MS+g_L[0];
  int nch=(Lt+127)>>7;
  if (lc>=nch) return;
  int l0=lc<<7, lv=min(128,Lt-l0);
  int tid=threadIdx.x, tm=tid>>4, tl=tid&15;
  int lane=tid&63, w=tid>>6;
  int bqn=bq*NW+n;
  int m0=mh*128;
  __shared__ __align__(16) float Qt[32*128];     // [o'][mm] 16KB (half of c)
  __shared__ __align__(16) float Kt[32*128];     // [o'][jj] 16KB (half of c)
  __shared__ unsigned long long colred[512];     // [w][128] 4KB
  const size_t qb=(size_t)bq*PD*MSP;
  const size_t kb=(size_t)(b*NW+n)*PD*LTCAP;
  float s[8][8]={};
  #pragma unroll
  for (int h=0;h<2;h++){
    __syncthreads();               // h=1: protect tiles from overwrite
    for (int k4=tid;k4<1024;k4+=256){
      int o=k4>>5, mq=k4&31;       // o' in 0..31, mq in 0..31 (4 cols each)
      int m=m0+mq*4;
      float4 v=make_float4(0.f,0.f,0.f,0.f);
      if (m<MSP) v=*(const float4*)&g_qproj[qb+(size_t)(h*32+o)*MSP+m];
      *(float4*)&Qt[o*128+mq*4]=v;
      *(float4*)&Kt[o*128+mq*4]=*(const float4*)&g_ksup[kb+(size_t)(h*32+o)*LTCAP+l0+mq*4];
    }
    __syncthreads();
    for (int c=0;c<32;c++){
      float a[8],b0[4],b1[4];
      *(float4*)&a[0]=*(const float4*)&Qt[c*128+tm*8];
      *(float4*)&a[4]=*(const float4*)&Qt[c*128+tm*8+4];
      *(float4*)b0=*(const float4*)&Kt[c*128+tl*4];
      *(float4*)b1=*(const float4*)&Kt[c*128+64+tl*4];
      #pragma unroll
      for (int i=0;i<8;i++)
        #pragma unroll
        for (int j=0;j<4;j++){ s[i][j]=fmaf(a[i],b0[j],s[i][j]); s[i][j+4]=fmaf(a[i],b1[j],s[i][j+4]); }
    }
  }
  #pragma unroll
  for (int i=0;i<8;i++)
    #pragma unroll
    for (int j=0;j<8;j++) s[i][j]*=0.125f;
  // persist scores for pass B (cols beyond Lt are exact zeros via zero K)
  #pragma unroll
  for (int i=0;i<8;i++){
    int m=m0+tm*8+i;
    if (m<MS){
      size_t sbase=((size_t)bqn*MSP+m)*SCAP+l0;
      *(float4*)&g_scores[sbase+tl*4]   =make_float4(s[i][0],s[i][1],s[i][2],s[i][3]);
      *(float4*)&g_scores[sbase+64+tl*4]=make_float4(s[i][4],s[i][5],s[i][6],s[i][7]);
    }
  }
  // row-best over this chunk's 128 cols -> atomic merge across lc blocks
  #pragma unroll
  for (int i=0;i<8;i++){
    int m=m0+tm*8+i;
    unsigned long long p=0ull;
    if (m<MS){
      #pragma unroll
      for (int j=0;j<8;j++){
        int jj=(j<4)?(tl*4+j):(64+tl*4+(j-4));
        if (jj<lv){
          unsigned long long c2=pk_make(s[i][j],l0+jj);
          if (c2>p) p=c2;
        }
      }
    }
    #pragma unroll
    for (int mk=1;mk<16;mk<<=1){ unsigned long long o=__shfl_xor(p,mk); if (o>p) p=o; }
    if (tl==0 && m<MS && p) atomicMax(&g_rowpack[(size_t)bqn*MSP+m],p);
  }
  // col-best over this block's 128 rows -> atomic merge across mh blocks
  #pragma unroll
  for (int j=0;j<8;j++){
    int jj=(j<4)?(tl*4+j):(64+tl*4+(j-4));
    unsigned long long p=0ull;
    #pragma unroll
    for (int i=0;i<8;i++){
      int m=m0+tm*8+i;
      if (m<MS){
        unsigned long long c2=pk_make(s[i][j],m);
        if (c2>p) p=c2;
      }
    }
    {
      unsigned long long o=__shfl_xor(p,16); if (o>p) p=o;
      o=__shfl_xor(p,32); if (o>p) p=o;
    }
    if ((lane>>4)==0) colred[w*128+jj]=p;
  }
  __syncthreads();
  if (tid<128 && tid<lv){
    unsigned long long p=colred[tid];
    if (colred[128+tid]>p) p=colred[128+tid];
    if (colred[256+tid]>p) p=colred[256+tid];
    if (colred[384+tid]>p) p=colred[384+tid];
    if (p) atomicMax(&g_snear2pack[(size_t)bqn*LTCAP+l0+tid],p);
  }
}

// ---------------- K8: q_mask + masked-row compaction ------------------------
__global__ __launch_bounds__(256) void k_qmask(){
  int bq=blockIdx.x;
  int tid=threadIdx.x, lane=tid&63, w=tid>>6;
  __shared__ int wtot[4];
  int base=0;
  for (int m0=0;m0<MS;m0+=256){
    int m=m0+tid;
    bool qm=false;
    if (m<MS){
      unsigned bhv=0u; unsigned long long bp=0ull; int bn=0;
      #pragma unroll
      for (int n=0;n<NW;n++){
        unsigned long long pk=g_rowpack[(size_t)(bq*NW+n)*MSP+m];
        unsigned hv=(unsigned)(pk>>32);
        if (hv>bhv){bhv=hv;bp=pk;bn=n;}
      }
      int bl=pk_idx(bp);
      qm=(pk_idx(g_snear2pack[(size_t)(bq*NW+bn)*LTCAP+bl])==m);
    }
    unsigned long long bal=__ballot(qm);
    if (lane==0) wtot[w]=(int)__popcll(bal);
    __syncthreads();
    int wpre=0, tot=0;
    #pragma unroll
    for (int ww=0;ww<4;ww++){ if (ww<w) wpre+=wtot[ww]; tot+=wtot[ww]; }
    if (qm){
      int pre=(int)__popcll(bal&((1ull<<lane)-1ull));
      g_qmrows[bq*MSP+base+wpre+pre]=m;
    }
    base+=tot;
    __syncthreads();
  }
  if (tid==0) g_qmcount[bq]=base;
}

// ---------------- K9: pass B — softmax(P) + PV + simi2, from stored scores --
// VERIFIED best configuration (652-654us total, ~153us passB, no spill):
// 64-row blocks, LDS 34.3KB (4 blocks/CU), launch_bounds(256,4), named
// prefetch regs. Retired levers (all measured worse): 32-row variants
// (rounds 8-11: scratch spill 4.4-4.7GB at every knob setting), kernel
// split into pv/fin/simi2 (round 13: +115us from intermediate round-trips
// + L3 thrash). This structure is the empirical optimum for this region.
#define EXPROW(i, svi) { \
    float e0=(tl*4+0<lv)?__expf((svi).x-rmax[i]):0.f; \
    float e1=(tl*4+1<lv)?__expf((svi).y-rmax[i]):0.f; \
    float e2=(tl*4+2<lv)?__expf((svi).z-rmax[i]):0.f; \
    float e3=(tl*4+3<lv)?__expf((svi).w-rmax[i]):0.f; \
    lsum[i]+=(e0+e1)+(e2+e3); \
    *(float4*)&Pt[(tm*4+(i))*68+tl*4]=make_float4(e0,e1,e2,e3); }
#define KPLOAD(kp, it, ktv) { int kk=tid+(it)*256; int o=kk>>4, kq=kk&15; \
    kp=*(const float4*)&g_vqn[qb+(size_t)o*MSP+(ktv)*64+kq*4]; }
#define KPSTORE(kp, it) { int kk=tid+(it)*256; int o=kk>>4, kq=kk&15; \
    *(float4*)&Vt[o*64+kq*4]=kp; }
__global__ __launch_bounds__(256,4) void k_passB(){
  int blk=blockIdx.x;
  int rt=blk%7; blk/=7;
  int n=blk%NW; blk/=NW;
  int bq=blk; int b=bq/Q;
  int nm=g_qmcount[bq];
  if (rt*64>=nm) return;
  int bqn=bq*NW+n;
  int Lt=MS+g_L[0];
  int nch=(Lt+63)>>6;
  int tid=threadIdx.x, tm=tid>>4, tl=tid&15;
  __shared__ __align__(16) float Vt[4096];     // V chunk [l][o] / vqn tile [o][k]
  __shared__ __align__(16) float Pt[64*68];    // stride 68: 16B-aligned rows, 2-way max
  __shared__ int rows_s[64];
  if (tid<64){ int g=rt*64+tid; rows_s[tid]=(g<nm)?g_qmrows[bq*MSP+g]:0; }
  __syncthreads();
  // per-thread row info: global row max (from pass A) + score-row base
  float rmax[4]; size_t sb[4];
  #pragma unroll
  for (int i=0;i<4;i++){
    int row=rows_s[tm*4+i];
    rmax[i]=dec_f((unsigned)(g_rowpack[(size_t)bqn*MSP+row]>>32));
    sb[i]=((size_t)bqn*MSP+row)*SCAP;
  }
  const size_t vb=(size_t)(b*NW+n)*LTCAP*PD;
  const size_t qb=(size_t)bq*PD*MSP;
  float lsum[4]={0.f,0.f,0.f,0.f};
  float acc[4][4]={};
  // prologue prefetch: chunk 0 scores + V (named regs, not arrays)
  float4 sv0,sv1,sv2,sv3, vp0,vp1,vp2,vp3;
  sv0=*(const float4*)&g_scores[sb[0]+tl*4];
  sv1=*(const float4*)&g_scores[sb[1]+tl*4];
  sv2=*(const float4*)&g_scores[sb[2]+tl*4];
  sv3=*(const float4*)&g_scores[sb[3]+tl*4];
  {
    const float* src=&g_vsupT[vb];
    vp0=*(const float4*)&src[(tid     )*4];
    vp1=*(const float4*)&src[(tid+256 )*4];
    vp2=*(const float4*)&src[(tid+512 )*4];
    vp3=*(const float4*)&src[(tid+768 )*4];
  }
  for (int lc=0;lc<nch;lc++){
    int l0=lc<<6, lv=min(64,Lt-l0);
    __syncthreads();                       // prev PV reads of Vt/Pt done
    // commit prefetched V to LDS
    *(float4*)&Vt[(tid     )*4]=vp0;
    *(float4*)&Vt[(tid+256 )*4]=vp1;
    *(float4*)&Vt[(tid+512 )*4]=vp2;
    *(float4*)&Vt[(tid+768 )*4]=vp3;
    // P = exp(s - rowmax) from prefetched scores; per-thread denominator
    EXPROW(0,sv0) EXPROW(1,sv1) EXPROW(2,sv2) EXPROW(3,sv3)
    __syncthreads();                       // Pt/Vt ready
    // issue next chunk's prefetch; latency hides under the PV loop below
    if (lc+1<nch){
      int l1=(lc+1)<<6;
      sv0=*(const float4*)&g_scores[sb[0]+l1+tl*4];
      sv1=*(const float4*)&g_scores[sb[1]+l1+tl*4];
      sv2=*(const float4*)&g_scores[sb[2]+l1+tl*4];
      sv3=*(const float4*)&g_scores[sb[3]+l1+tl*4];
      const float* src=&g_vsupT[vb+(size_t)l1*PD];
      vp0=*(const float4*)&src[(tid     )*4];
      vp1=*(const float4*)&src[(tid+256 )*4];
      vp2=*(const float4*)&src[(tid+512 )*4];
      vp3=*(const float4*)&src[(tid+768 )*4];
    }
    // PV: acc[i][j] += P[row_i][l] * V[l][tl*4+j]
    for (int l4=0;l4<64;l4+=4){
      float4 pq[4];
      #pragma unroll
      for (int i=0;i<4;i++) pq[i]=*(const float4*)&Pt[(tm*4+i)*68+l4];
      #pragma unroll
      for (int u=0;u<4;u++){
        float4 v4=*(const float4*)&Vt[(l4+u)*64+tl*4];
        #pragma unroll
        for (int i=0;i<4;i++){
          float p=((const float*)&pq[i])[u];
          acc[i][0]=fmaf(p,v4.x,acc[i][0]);
          acc[i][1]=fmaf(p,v4.y,acc[i][1]);
          acc[i][2]=fmaf(p,v4.z,acc[i][2]);
          acc[i][3]=fmaf(p,v4.w,acc[i][3]);
        }
      }
    }
  } // lc
  // prefetch simi2 kt=0 vqn tile early (hides under finalize)
  float4 kp0,kp1,kp2,kp3;
  KPLOAD(kp0,0,0) KPLOAD(kp1,1,0) KPLOAD(kp2,2,0) KPLOAD(kp3,3,0)
  // finalize: denominator reduce (once), normalize, L2-normalize rows
  float rn[4];
  #pragma unroll
  for (int i=0;i<4;i++){
    float ls=lsum[i];
    #pragma unroll
    for (int mk=1;mk<16;mk<<=1) ls+=__shfl_xor(ls,mk);
    float ss=0.f;
    #pragma unroll
    for (int j=0;j<4;j++){ acc[i][j]/=ls; ss=fmaf(acc[i][j],acc[i][j],ss); }
    #pragma unroll
    for (int mk=1;mk<16;mk<<=1) ss+=__shfl_xor(ss,mk);
    rn[i]=1.f/(sqrtf(ss)+1e-16f);
  }
  __syncthreads();                         // last PV reads of Pt done
  #pragma unroll
  for (int i=0;i<4;i++)
    *(float4*)&Pt[(tm*4+i)*68+tl*4]=make_float4(acc[i][0],acc[i][1],acc[i][2],acc[i][3]);
  int rowok[4];
  #pragma unroll
  for (int i=0;i<4;i++) rowok[i]=(rt*64+tm*4+i<nm);
  for (int kt=0;kt<7;kt++){
    __syncthreads();
    KPSTORE(kp0,0) KPSTORE(kp1,1) KPSTORE(kp2,2) KPSTORE(kp3,3)
    __syncthreads();
    // prefetch next vqn tile; hides under the d-GEMM below
    if (kt+1<7){
      KPLOAD(kp0,0,kt+1) KPLOAD(kp1,1,kt+1) KPLOAD(kp2,2,kt+1) KPLOAD(kp3,3,kt+1)
    }
    float d[4][4]={};
    for (int o=0;o<64;o++){
      float a[4], bv4[4];
      #pragma unroll
      for (int i=0;i<4;i++) a[i]=Pt[(tm*4+i)*68+o];
      *(float4*)bv4=*(const float4*)&Vt[o*64+tl*4];
      #pragma unroll
      for (int i=0;i<4;i++)
        #pragma unroll
        for (int j=0;j<4;j++) d[i][j]=fmaf(a[i],bv4[j],d[i][j]);
    }
    #pragma unroll
    for (int j=0;j<4;j++){
      int kg=kt*64+tl*4+j;
      float mv=NEGF;
      #pragma unroll
      for (int i=0;i<4;i++) if (rowok[i]) mv=fmaxf(mv,d[i][j]*rn[i]);
      mv=fmaxf(mv,__shfl_xor(mv,16));
      mv=fmaxf(mv,__shfl_xor(mv,32));
      if (((tid>>4)&3)==0 && kg<MS && mv>-1e37f)
        atomicMax(&g_cmax[(size_t)bqn*MSP+kg],enc_f(mv));
    }
  }
}

// ---------------- K10: logits (with fused vbar contribution) ----------------
__global__ __launch_bounds__(256) void k_logits(){
  int bqn=blockIdx.x;
  int n=bqn%NW, bq=bqn/NW, b=bq/Q;
  int tid=threadIdx.x;
  int nm=g_qmcount[bq];
  __shared__ float red[256];
  __shared__ float vb_s[64];
  if (tid<64) vb_s[tid]=g_vbarn[(b*NW+n)*PD+tid];
  __syncthreads();
  const float* vq=&g_vqn[(size_t)bq*PD*MSP];
  float p=0.f;
  for (int k=tid;k<MS;k+=256){
    float v=dec_f(g_cmax[(size_t)bqn*MSP+k]);
    if (nm<MS){
      float d=0.f;
      for (int o=0;o<PD;o++) d=fmaf(vb_s[o],vq[(size_t)o*MSP+k],d);
      v=fmaxf(v,d);
    }
    p+=(v+1.f)*0.5f;
  }
  red[tid]=p; __syncthreads();
  for (int s=128;s;s>>=1){ if (tid<s) red[tid]+=red[tid+s]; __syncthreads(); }
  if (tid==0) g_logits[bqn]=red[0];
}

// ---------------- K11: NLL loss ---------------------------------------------
__global__ void k_loss(const int* __restrict__ qy, float* __restrict__ out){
  int t=threadIdx.x;
  float lp=0.f;
  if (t<B*Q){
    int y=qy[t];
    float xv[NW]; float mxv=NEGF;
    #pragma unroll
    for (int n=0;n<NW;n++){ xv[n]=g_logits[t*NW+n]*5.f; mxv=fmaxf(mxv,xv[n]); }
    float s=0.f, xy=0.f;
    #pragma unroll
    for (int n=0;n<NW;n++){ s+=__expf(xv[n]-mxv); if (n==y) xy=xv[n]; }
    lp=xy-mxv-logf(s);
  }
  #pragma unroll
  for (int off=32;off;off>>=1) lp+=__shfl_down(lp,off);
  if (t==0) out[0]=-lp/(float)(B*Q);
}

extern "C" void kernel_launch(void* const* d_in, const int* in_sizes, int n_in,
                              void* d_out, int out_size, void* d_ws, size_t ws_size,
                              hipStream_t stream) {
  (void)in_sizes; (void)n_in; (void)out_size; (void)d_ws; (void)ws_size;
  const float* sup=(const float*)d_in[0];
  const float* qx =(const float*)d_in[2];
  const int*   qy =(const int*)d_in[3];
  const float* unl=(const float*)d_in[4];
  const float* kw =(const float*)d_in[5];
  const float* qw =(const float*)d_in[6];
  const float* vw =(const float*)d_in[7];
  float* out=(float*)d_out;

  k_init   <<<525,256,0,stream>>>();     // covers B*Q*NW*LTCAP = 134400
  k_norms  <<<69,256,0,stream>>>(sup,unl);
  k_u2s    <<<B*69*18,256,0,stream>>>();
  k_compact<<<B*NW,256,0,stream>>>();
  k_kv     <<<B*NW*(LTCAP/64),256,0,stream>>>(sup,unl,kw,vw);
  k_vbar   <<<B*NW,256,0,stream>>>();
  k_qproj  <<<B*Q*7,256,0,stream>>>(qx,qw,vw);
  k_passA  <<<B*Q*NW*28,256,0,stream>>>();
  k_qmask  <<<B*Q,256,0,stream>>>();
  k_passB  <<<B*Q*NW*7,256,0,stream>>>();
  k_logits <<<B*Q*NW,256,0,stream>>>();
  k_loss   <<<1,64,0,stream>>>(qy,out);
}